// Round 14
// baseline (332.538 us; speedup 1.0000x reference)
//
#include <hip/hip_runtime.h>
#include <hip/hip_bf16.h>
#include <math.h>
#include <type_traits>

#define NEG_SLOPE 0.2f
#define CAP 64           // fixed CSR row capacity (max in-degree+1; Poisson(16) -> P(>=64) ~ 1e-13)

typedef float f32x4 __attribute__((ext_vector_type(4)));
typedef short s16x8 __attribute__((ext_vector_type(8)));
typedef short s16x4 __attribute__((ext_vector_type(4)));

__device__ __forceinline__ float bf2f(ushort s) {
    union { unsigned u; float f; } cv; cv.u = ((unsigned)s) << 16;
    return cv.f;
}
__device__ __forceinline__ ushort f2bf(float f) {
    __hip_bfloat16 b = __float2bfloat16(f);
    union { __hip_bfloat16 b; ushort u; } cv; cv.b = b;
    return cv.u;
}

// ---------- edge dtype handling (int32 vs int64 little-endian) ----------
__device__ __forceinline__ int edge_val(const int* e, long long i, int is64) {
    return is64 ? e[(size_t)(2 * i)] : e[(size_t)i];
}

// ---------- prep: W1t | W2t | w2s,w2d (= W2 @ att_{s,d}2) | counts=0 ----------
__global__ __launch_bounds__(256) void prep_k(
        const float* __restrict__ W1, ushort* __restrict__ W1t, int K1, int N1,
        const float* __restrict__ W2, ushort* __restrict__ W2t, int K2, int N2,
        const float* __restrict__ aS2, const float* __restrict__ aD2,
        float* __restrict__ w2s, float* __restrict__ w2d,
        int* __restrict__ counts, int N, int nbW1, int nbW2) {
    int b = blockIdx.x, tid = threadIdx.x;
    if (b < nbW1) {
        int idx = b * 256 + tid;
        if (idx < K1 * N1) {
            int k = idx & (K1 - 1), n = idx / K1;
            W1t[(size_t)n * K1 + k] = f2bf(W1[(size_t)k * N1 + n]);
        }
        return;
    }
    b -= nbW1;
    if (b < nbW2) {
        int idx = b * 256 + tid;
        if (idx < K2 * N2) {
            int k = idx & (K2 - 1), n = idx / K2;
            W2t[(size_t)n * K2 + k] = f2bf(W2[(size_t)k * N2 + n]);
        }
        return;
    }
    b -= nbW2;
    if (b < 2) {                               // w2s[k] = sum_c W2[k][c]*aS2[c]; w2d likewise
        int k = b * 256 + tid;                 // K2 = 512
        if (k < K2) {
            float s = 0.f, d = 0.f;
            for (int c = 0; c < N2; ++c) {
                float w = W2[(size_t)k * N2 + c];
                s += w * aS2[c];
                d += w * aD2[c];
            }
            w2s[k] = s; w2d[k] = d;
        }
        return;
    }
    b -= 2;
    int i = b * 256 + tid;
    if (i < N) counts[i] = 0;
}

// ---------- layer-1 GEMM: two-phase B-resident (A loaded ONCE) + scatter tail ----------
// Gemm blocks g in [0, nGemm): row-stripe by=g; phase px stages W1t cols px*256..+256
// into LDS (135KB), A fp32 streamed to regs once (in-register bf16 convert).
// Tail blocks: CSR scatter (atomicAdd slot), overlapping retiring GEMM blocks.
__global__ __launch_bounds__(512) void gemm1_scatter(
        const float* __restrict__ A, const ushort* __restrict__ Bt,
        ushort* __restrict__ C, const float* __restrict__ att_s,
        const float* __restrict__ att_d, float* __restrict__ as_,
        float* __restrict__ ad_, int M, int Ntot, int nGemm,
        const int* __restrict__ ebuf, int E, int Nn,
        int* __restrict__ counts, int* __restrict__ csr) {
    int g = blockIdx.x;
    if (g < nGemm) {
        constexpr int KK = 256, NCOLS = 256, NT = 16;
        __shared__ __align__(16) ushort Bs[NCOLS][KK + 8];
        int tid = threadIdx.x;
        int wid = tid >> 6, lane = tid & 63;
        int l15 = lane & 15, l4 = lane >> 4;
        int mbase = g * 128 + wid * 16;
        int rowA = mbase + l15; if (rowA >= M) rowA = M - 1;

        // stream A row slice once (fp32 -> bf16 in registers)
        s16x8 af[8];
        {
            const float* Ap = A + (size_t)rowA * KK + (l4 << 3);
#pragma unroll
            for (int ks = 0; ks < 8; ++ks) {
                float4 u0 = *(const float4*)&Ap[ks * 32];
                float4 u1 = *(const float4*)&Ap[ks * 32 + 4];
                s16x8 w;
                w[0] = (short)f2bf(u0.x); w[1] = (short)f2bf(u0.y);
                w[2] = (short)f2bf(u0.z); w[3] = (short)f2bf(u0.w);
                w[4] = (short)f2bf(u1.x); w[5] = (short)f2bf(u1.y);
                w[6] = (short)f2bf(u1.z); w[7] = (short)f2bf(u1.w);
                af[ks] = w;
            }
        }

#pragma unroll
        for (int px = 0; px < 2; ++px) {
            int bn = px * NCOLS;
            // stage this phase's B panel
#pragma unroll
            for (int p = 0; p < 16; ++p) {
                int idx = p * 512 + tid;
                int n = idx >> 5;
                int kc = (idx & 31) << 3;
                *(s16x8*)&Bs[n][kc] = *(const s16x8*)&Bt[(size_t)(bn + n) * KK + kc];
            }
            __syncthreads();
            f32x4 acc[NT] = {};
#pragma unroll
            for (int nt = 0; nt < NT; ++nt)
#pragma unroll
                for (int ks = 0; ks < 8; ++ks) {
                    s16x8 bfr = *(const s16x8*)&Bs[nt * 16 + l15][ks * 32 + (l4 << 3)];
                    acc[nt] = __builtin_amdgcn_mfma_f32_16x16x32_bf16(af[ks], bfr, acc[nt], 0, 0, 0);
                }
            __syncthreads();                    // all waves done reading Bs
            // epilogue: C + fused attn logits for heads px*4 .. px*4+3
#pragma unroll
            for (int h = 0; h < 4; ++h) {
                int head = px * 4 + h;
                float asv[4], adv[4];
#pragma unroll
                for (int t = 0; t < 4; ++t) {
                    asv[t] = att_s[head * 64 + t * 16 + l15];
                    adv[t] = att_d[head * 64 + t * 16 + l15];
                }
#pragma unroll
                for (int j = 0; j < 4; ++j) {
                    int r = mbase + (l4 << 2) + j;
                    float ps = 0.f, pd = 0.f;
#pragma unroll
                    for (int t = 0; t < 4; ++t) {
                        float v = acc[h * 4 + t][j];
                        ps += v * asv[t];
                        pd += v * adv[t];
                    }
#pragma unroll
                    for (int off = 1; off < 16; off <<= 1) {
                        ps += __shfl_xor(ps, off);
                        pd += __shfl_xor(pd, off);
                    }
                    if (r < M) {
                        if (l15 == 0) {
                            as_[(size_t)r * 8 + head] = ps;
                            ad_[(size_t)r * 8 + head] = pd;
                        }
#pragma unroll
                        for (int t = 0; t < 4; ++t)
                            C[(size_t)r * Ntot + head * 64 + t * 16 + l15] = f2bf(acc[h * 4 + t][j]);
                    }
                }
            }
        }
        return;
    }
    // ---- CSR scatter tail ----
    __shared__ int s_is64;
    if (threadIdx.x < 64) {
        int v = ebuf[2 * threadIdx.x + 1];      // odd slots zero => int64
        unsigned long long bl = __ballot(v != 0);
        if (threadIdx.x == 0) s_is64 = (bl == 0ull) ? 1 : 0;
    }
    __syncthreads();
    int is64 = s_is64;
    int i = (g - nGemm) * 512 + threadIdx.x;
    if (i >= E + Nn) return;
    int s, d;
    if (i < E) {
        s = edge_val(ebuf, i, is64);
        d = edge_val(ebuf, (long long)E + i, is64);
    } else {
        s = i - E; d = s;                       // self-loop
    }
    int pos = atomicAdd(&counts[d], 1);
    if (pos < CAP) csr[(size_t)d * CAP + pos] = s;
}

// ---------- layer-1 fused: softmax+aggregate + IN-REGISTER gemm2 + attn-logits-2 ----------
// One wave per node, no barriers, no LDS. After the gather, lane l holds post-relu
// out1 channels [8l,8l+8) in rr[]; h2 = rr-row @ W2 via 4-channel reduce-scatter
// chunks (W2t rows L2-hot); as2/ad2 via linearity: as2 = rr . w2s (w2s = W2@att_s2).
// out1 is NEVER written to memory.
__global__ __launch_bounds__(256) void gat_fused_l1(
        const ushort* __restrict__ h, const float* __restrict__ as_,
        const float* __restrict__ ad_, const int* __restrict__ counts,
        const int* __restrict__ csr, const float* __restrict__ bias,
        const ushort* __restrict__ W2t, const float* __restrict__ w2s,
        const float* __restrict__ w2d, ushort* __restrict__ h2,
        float* __restrict__ as2, float* __restrict__ ad2, int N) {
    int n = (blockIdx.x * 256 + threadIdx.x) >> 6;
    if (n >= N) return;
    int l = threadIdx.x & 63;
    size_t base = (size_t)n * CAP;
    int deg = counts[n]; deg = deg > CAP ? CAP : deg;

    // ---- stats: lane (edge = l>>3, head = l&7); 32B-coalesced as_ reads ----
    int hh = l & 7, e0 = l >> 3;
    float adw = ad_[n * 8 + hh];
    float m = -1e30f, s = 0.f;
    for (int k = e0; k < deg; k += 8) {
        int src = csr[base + k];
        float e = as_[src * 8 + hh] + adw;
        e = e > 0.f ? e : NEG_SLOPE * e;
        float mn = fmaxf(m, e);
        s = s * __expf(m - mn) + __expf(e - mn);
        m = mn;
    }
#pragma unroll
    for (int off = 8; off < 64; off <<= 1) {
        float mo = __shfl_xor(m, off), so = __shfl_xor(s, off);
        float mn = fmaxf(m, mo);
        s = s * __expf(m - mn) + so * __expf(mo - mn);
        m = mn;
    }
    float inv = 1.f / (s + 1e-16f);
    int hd = l >> 3;                               // head of this lane in gather mapping
    float mh   = __shfl(m, hd);
    float invh = __shfl(inv, hd);
    float adh  = __shfl(adw, hd);

    // ---- gather: one 1KB row per edge (lane l -> ch [8l,8l+8)); unroll x4 ----
    float acc[8] = {};
    int k = 0;
    for (; k + 4 <= deg; k += 4) {
        int s0 = csr[base + k],     s1 = csr[base + k + 1];
        int s2 = csr[base + k + 2], s3 = csr[base + k + 3];
        s16x8 v0 = *(const s16x8*)&h[((size_t)s0 << 9) + (l << 3)];
        s16x8 v1 = *(const s16x8*)&h[((size_t)s1 << 9) + (l << 3)];
        s16x8 v2 = *(const s16x8*)&h[((size_t)s2 << 9) + (l << 3)];
        s16x8 v3 = *(const s16x8*)&h[((size_t)s3 << 9) + (l << 3)];
        float e0v = as_[s0 * 8 + hd] + adh;
        float e1v = as_[s1 * 8 + hd] + adh;
        float e2v = as_[s2 * 8 + hd] + adh;
        float e3v = as_[s3 * 8 + hd] + adh;
        e0v = e0v > 0.f ? e0v : NEG_SLOPE * e0v;
        e1v = e1v > 0.f ? e1v : NEG_SLOPE * e1v;
        e2v = e2v > 0.f ? e2v : NEG_SLOPE * e2v;
        e3v = e3v > 0.f ? e3v : NEG_SLOPE * e3v;
        float a0 = __expf(e0v - mh);
        float a1 = __expf(e1v - mh);
        float a2 = __expf(e2v - mh);
        float a3 = __expf(e3v - mh);
#pragma unroll
        for (int j = 0; j < 8; ++j)
            acc[j] += a0 * bf2f((ushort)v0[j]) + a1 * bf2f((ushort)v1[j])
                    + a2 * bf2f((ushort)v2[j]) + a3 * bf2f((ushort)v3[j]);
    }
    for (; k < deg; ++k) {
        int s0 = csr[base + k];
        s16x8 v0 = *(const s16x8*)&h[((size_t)s0 << 9) + (l << 3)];
        float e0v = as_[s0 * 8 + hd] + adh;
        e0v = e0v > 0.f ? e0v : NEG_SLOPE * e0v;
        float a0 = __expf(e0v - mh);
#pragma unroll
        for (int j = 0; j < 8; ++j) acc[j] += a0 * bf2f((ushort)v0[j]);
    }

    // ---- post-relu out1 row in registers ----
    float4 b0 = *(const float4*)&bias[l * 8];
    float4 b1 = *(const float4*)&bias[l * 8 + 4];
    float rr[8];
    rr[0] = fmaxf(acc[0] * invh + b0.x, 0.f);
    rr[1] = fmaxf(acc[1] * invh + b0.y, 0.f);
    rr[2] = fmaxf(acc[2] * invh + b0.z, 0.f);
    rr[3] = fmaxf(acc[3] * invh + b0.w, 0.f);
    rr[4] = fmaxf(acc[4] * invh + b1.x, 0.f);
    rr[5] = fmaxf(acc[5] * invh + b1.y, 0.f);
    rr[6] = fmaxf(acc[6] * invh + b1.z, 0.f);
    rr[7] = fmaxf(acc[7] * invh + b1.w, 0.f);

    // ---- as2/ad2 via linearity: as2[n] = rr . w2s ----
    {
        float4 wsa = *(const float4*)&w2s[l << 3];
        float4 wsb = *(const float4*)&w2s[(l << 3) + 4];
        float4 wda = *(const float4*)&w2d[l << 3];
        float4 wdb = *(const float4*)&w2d[(l << 3) + 4];
        float ps = rr[0] * wsa.x + rr[1] * wsa.y + rr[2] * wsa.z + rr[3] * wsa.w
                 + rr[4] * wsb.x + rr[5] * wsb.y + rr[6] * wsb.z + rr[7] * wsb.w;
        float pd = rr[0] * wda.x + rr[1] * wda.y + rr[2] * wda.z + rr[3] * wda.w
                 + rr[4] * wdb.x + rr[5] * wdb.y + rr[6] * wdb.z + rr[7] * wdb.w;
#pragma unroll
        for (int off = 1; off < 64; off <<= 1) {
            ps += __shfl_xor(ps, off);
            pd += __shfl_xor(pd, off);
        }
        if (l == 0) { as2[n] = ps; ad2[n] = pd; }
    }

    // ---- fused gemm2: h2[n][c] = sum_k rr_row[k] * W2[k][c], 4 channels per chunk ----
#pragma unroll
    for (int cc = 0; cc < 16; ++cc) {
        int c0 = cc * 4;
        s16x8 q0 = *(const s16x8*)&W2t[(size_t)(c0 + 0) * 512 + (l << 3)];
        s16x8 q1 = *(const s16x8*)&W2t[(size_t)(c0 + 1) * 512 + (l << 3)];
        s16x8 q2 = *(const s16x8*)&W2t[(size_t)(c0 + 2) * 512 + (l << 3)];
        s16x8 q3 = *(const s16x8*)&W2t[(size_t)(c0 + 3) * 512 + (l << 3)];
        float p0 = 0.f, p1 = 0.f, p2 = 0.f, p3 = 0.f;
#pragma unroll
        for (int j = 0; j < 8; ++j) {
            p0 += rr[j] * bf2f((ushort)q0[j]);
            p1 += rr[j] * bf2f((ushort)q1[j]);
            p2 += rr[j] * bf2f((ushort)q2[j]);
            p3 += rr[j] * bf2f((ushort)q3[j]);
        }
        // reduce-scatter 4 channels over 64 lanes
        float t0 = __shfl_xor(p0, 1), t2 = __shfl_xor(p2, 1);
        float t1 = __shfl_xor(p1, 1), t3 = __shfl_xor(p3, 1);
        float u0 = (l & 1) ? p2 + t2 : p0 + t0;   // ch = c0 + (l&1)*2
        float u1 = (l & 1) ? p3 + t3 : p1 + t1;   // ch = c0 + 1 + (l&1)*2
        float s0 = __shfl_xor(u0, 2), s1 = __shfl_xor(u1, 2);
        float v = (l & 2) ? u1 + s1 : u0 + s0;    // ch = c0 + (l&1)*2 + ((l&2)?1:0)
        v += __shfl_xor(v, 4);
        v += __shfl_xor(v, 8);
        v += __shfl_xor(v, 16);
        v += __shfl_xor(v, 32);
        if (l < 4) h2[((size_t)n << 6) + c0 + ((l & 1) << 1) + ((l >> 1) & 1)] = f2bf(v);
    }
}

// ---------- layer-2 fused: wave per node; quarter-wave per edge (128B bf16 row) ----------
__global__ __launch_bounds__(256) void gat_fused_l2(
        const ushort* __restrict__ h, const float* __restrict__ as_,
        const float* __restrict__ ad_, const int* __restrict__ counts,
        const int* __restrict__ csr, const float* __restrict__ bias,
        float* __restrict__ out, int N) {
    int n = (blockIdx.x * 256 + threadIdx.x) >> 6;
    if (n >= N) return;
    int l = threadIdx.x & 63;
    size_t base = (size_t)n * CAP;
    int deg = counts[n]; deg = deg > CAP ? CAP : deg;
    float adv = ad_[n];

    float m = -1e30f, s = 0.f;
    for (int k = l; k < deg; k += 64) {
        float e = as_[csr[base + k]] + adv;
        e = e > 0.f ? e : NEG_SLOPE * e;
        float mn = fmaxf(m, e);
        s = s * __expf(m - mn) + __expf(e - mn);
        m = mn;
    }
#pragma unroll
    for (int off = 1; off < 64; off <<= 1) {
        float mo = __shfl_xor(m, off), so = __shfl_xor(s, off);
        float mn = fmaxf(m, mo);
        s = s * __expf(m - mn) + so * __expf(mo - mn);
        m = mn;
    }
    float inv = 1.f / (s + 1e-16f);

    int q = l >> 4, c4 = l & 15;
    float a0 = 0.f, a1 = 0.f, a2 = 0.f, a3 = 0.f;
    int k = q;
    for (; k + 12 < deg; k += 16) {
        int sA = csr[base + k],     sB = csr[base + k + 4];
        int sC = csr[base + k + 8], sD = csr[base + k + 12];
        s16x4 vA = *(const s16x4*)&h[((size_t)sA << 6) + (c4 << 2)];
        s16x4 vB = *(const s16x4*)&h[((size_t)sB << 6) + (c4 << 2)];
        s16x4 vC = *(const s16x4*)&h[((size_t)sC << 6) + (c4 << 2)];
        s16x4 vD = *(const s16x4*)&h[((size_t)sD << 6) + (c4 << 2)];
        float eA = as_[sA] + adv, eB = as_[sB] + adv;
        float eC = as_[sC] + adv, eD = as_[sD] + adv;
        eA = eA > 0.f ? eA : NEG_SLOPE * eA;
        eB = eB > 0.f ? eB : NEG_SLOPE * eB;
        eC = eC > 0.f ? eC : NEG_SLOPE * eC;
        eD = eD > 0.f ? eD : NEG_SLOPE * eD;
        float aA = __expf(eA - m), aB = __expf(eB - m);
        float aC = __expf(eC - m), aD = __expf(eD - m);
        a0 += aA * bf2f((ushort)vA[0]) + aB * bf2f((ushort)vB[0])
            + aC * bf2f((ushort)vC[0]) + aD * bf2f((ushort)vD[0]);
        a1 += aA * bf2f((ushort)vA[1]) + aB * bf2f((ushort)vB[1])
            + aC * bf2f((ushort)vC[1]) + aD * bf2f((ushort)vD[1]);
        a2 += aA * bf2f((ushort)vA[2]) + aB * bf2f((ushort)vB[2])
            + aC * bf2f((ushort)vC[2]) + aD * bf2f((ushort)vD[2]);
        a3 += aA * bf2f((ushort)vA[3]) + aB * bf2f((ushort)vB[3])
            + aC * bf2f((ushort)vC[3]) + aD * bf2f((ushort)vD[3]);
    }
    for (; k < deg; k += 4) {
        int sA = csr[base + k];
        s16x4 vA = *(const s16x4*)&h[((size_t)sA << 6) + (c4 << 2)];
        float eA = as_[sA] + adv;
        eA = eA > 0.f ? eA : NEG_SLOPE * eA;
        float aA = __expf(eA - m);
        a0 += aA * bf2f((ushort)vA[0]);
        a1 += aA * bf2f((ushort)vA[1]);
        a2 += aA * bf2f((ushort)vA[2]);
        a3 += aA * bf2f((ushort)vA[3]);
    }
    a0 += __shfl_xor(a0, 16); a0 += __shfl_xor(a0, 32);
    a1 += __shfl_xor(a1, 16); a1 += __shfl_xor(a1, 32);
    a2 += __shfl_xor(a2, 16); a2 += __shfl_xor(a2, 32);
    a3 += __shfl_xor(a3, 16); a3 += __shfl_xor(a3, 32);
    if (q == 0) {
        float4 bv = *(const float4*)&bias[c4 << 2];
        float4 r;
        r.x = a0 * inv + bv.x; r.y = a1 * inv + bv.y;
        r.z = a2 * inv + bv.z; r.w = a3 * inv + bv.w;
        *(float4*)&out[((size_t)n << 6) + (c4 << 2)] = r;
    }
}

// ---------- launch ----------
extern "C" void kernel_launch(void* const* d_in, const int* in_sizes, int n_in,
                              void* d_out, int out_size, void* d_ws, size_t ws_size,
                              hipStream_t stream) {
    const float* x    = (const float*)d_in[0];
    const int*   ebuf = (const int*)d_in[1];
    const float* W1   = (const float*)d_in[2];
    const float* aS1  = (const float*)d_in[3];
    const float* aD1  = (const float*)d_in[4];
    const float* b1   = (const float*)d_in[5];
    const float* W2   = (const float*)d_in[6];
    const float* aS2  = (const float*)d_in[7];
    const float* aD2  = (const float*)d_in[8];
    const float* b2   = (const float*)d_in[9];
    float* out = (float*)d_out;

    const int F_in = 256, H1 = 8, HC1 = 512, C2 = 64;
    int N = in_sizes[0] / F_in;   // 50000
    int E = in_sizes[1] / 2;      // 800000

    char* ws = (char*)d_ws;
    size_t off = 0;
    auto alloc = [&](size_t bytes) -> void* {
        void* p = ws + off;
        off = (off + bytes + 255) & ~(size_t)255;
        return p;
    };
    ushort* h1b    = (ushort*)alloc((size_t)N * HC1 * 2);
    ushort* h2b    = (ushort*)alloc((size_t)N * C2 * 2);
    float* as1     = (float*)alloc((size_t)N * H1 * 4);
    float* ad1     = (float*)alloc((size_t)N * H1 * 4);
    float* as2     = (float*)alloc((size_t)N * 4);
    float* ad2     = (float*)alloc((size_t)N * 4);
    int*   counts  = (int*)alloc((size_t)N * 4);
    int*   csr     = (int*)alloc((size_t)N * CAP * 4);
    ushort* W1t    = (ushort*)alloc((size_t)F_in * HC1 * 2);
    ushort* W2t    = (ushort*)alloc((size_t)HC1 * C2 * 2);
    float* w2s     = (float*)alloc((size_t)HC1 * 4);
    float* w2d     = (float*)alloc((size_t)HC1 * 4);

    int nbW1 = (F_in * HC1 + 255) >> 8;        // 512
    int nbW2 = (HC1 * C2 + 255) >> 8;          // 128
    int nbZ  = (N + 255) >> 8;                 // 196

    // 1) prep: W transposes, w2s/w2d, counts zeroing
    prep_k<<<nbW1 + nbW2 + 2 + nbZ, 256, 0, stream>>>(
        W1, W1t, F_in, HC1, W2, W2t, HC1, C2, aS2, aD2, w2s, w2d,
        counts, N, nbW1, nbW2);

    // 2) layer-1 GEMM (two-phase B-resident, A once) + CSR scatter tail
    {
        int nGemm = (N + 127) / 128;           // 391
        int nScatter = (E + N + 511) / 512;    // 1660
        gemm1_scatter<<<nGemm + nScatter, 512, 0, stream>>>(
            x, W1t, h1b, aS1, aD1, as1, ad1, N, HC1, nGemm,
            ebuf, E, N, counts, csr);
    }

    // 3) layer-1 fused: softmax+aggregate + in-register gemm2 + attn-logits-2
    gat_fused_l1<<<(N + 3) / 4, 256, 0, stream>>>(
        h1b, as1, ad1, counts, csr, b1, W2t, w2s, w2d, h2b, as2, ad2, N);

    // 4) layer-2 fused softmax+aggregate
    gat_fused_l2<<<(N + 3) / 4, 256, 0, stream>>>(h2b, as2, ad2, counts, csr, b2, out, N);
}

// Round 15
// 260.661 us; speedup vs baseline: 1.2757x; 1.2757x over previous
//
#include <hip/hip_runtime.h>
#include <hip/hip_bf16.h>
#include <math.h>
#include <type_traits>

#define NEG_SLOPE 0.2f
#define CAP 64           // fixed CSR row capacity (max in-degree+1; Poisson(16) -> P(>=64) ~ 1e-13)

typedef float f32x4 __attribute__((ext_vector_type(4)));
typedef short s16x8 __attribute__((ext_vector_type(8)));
typedef short s16x4 __attribute__((ext_vector_type(4)));

__device__ __forceinline__ float bf2f(ushort s) {
    union { unsigned u; float f; } cv; cv.u = ((unsigned)s) << 16;
    return cv.f;
}
__device__ __forceinline__ ushort f2bf(float f) {
    __hip_bfloat16 b = __float2bfloat16(f);
    union { __hip_bfloat16 b; ushort u; } cv; cv.b = b;
    return cv.u;
}

// ---------- edge dtype handling (int32 vs int64 little-endian) ----------
__device__ __forceinline__ int edge_val(const int* e, long long i, int is64) {
    return is64 ? e[(size_t)(2 * i)] : e[(size_t)i];
}

// ---------- prep: W1t | W2t | counts=0 (no LDS, tiny) ----------
__global__ __launch_bounds__(256) void prep_k(
        const float* __restrict__ W1, ushort* __restrict__ W1t, int K1, int N1,
        const float* __restrict__ W2, ushort* __restrict__ W2t, int K2, int N2,
        int* __restrict__ counts, int N, int nbW1, int nbW2) {
    int b = blockIdx.x, tid = threadIdx.x;
    if (b < nbW1) {
        int idx = b * 256 + tid;
        if (idx < K1 * N1) {
            int k = idx & (K1 - 1), n = idx / K1;
            W1t[(size_t)n * K1 + k] = f2bf(W1[(size_t)k * N1 + n]);
        }
        return;
    }
    b -= nbW1;
    if (b < nbW2) {
        int idx = b * 256 + tid;
        if (idx < K2 * N2) {
            int k = idx & (K2 - 1), n = idx / K2;
            W2t[(size_t)n * K2 + k] = f2bf(W2[(size_t)k * N2 + n]);
        }
        return;
    }
    b -= nbW2;
    int i = b * 256 + tid;
    if (i < N) counts[i] = 0;
}

// ---------- layer-1 GEMM: 4-phase B-resident (A loaded ONCE; 2 blocks/CU) + scatter tail ----
// Gemm blocks g in [0, nGemm): row-stripe by=g. Phase px stages W1t cols px*128..+128
// into 67.6KB LDS; A fp32 streamed to regs once (in-register bf16 convert).
// Tail blocks: CSR scatter (atomicAdd slot), overlapping retiring GEMM blocks.
__global__ __launch_bounds__(512) void gemm1_scatter(
        const float* __restrict__ A, const ushort* __restrict__ Bt,
        ushort* __restrict__ C, const float* __restrict__ att_s,
        const float* __restrict__ att_d, float* __restrict__ as_,
        float* __restrict__ ad_, int M, int Ntot, int nGemm,
        const int* __restrict__ ebuf, int E, int Nn,
        int* __restrict__ counts, int* __restrict__ csr) {
    int g = blockIdx.x;
    if (g < nGemm) {
        constexpr int KK = 256, NCOLS = 128, NT = 8;
        __shared__ __align__(16) ushort Bs[NCOLS][KK + 8];
        int tid = threadIdx.x;
        int wid = tid >> 6, lane = tid & 63;
        int l15 = lane & 15, l4 = lane >> 4;
        int mbase = g * 128 + wid * 16;
        int rowA = mbase + l15; if (rowA >= M) rowA = M - 1;

        // stream A row slice once (fp32 -> bf16 in registers)
        s16x8 af[8];
        {
            const float* Ap = A + (size_t)rowA * KK + (l4 << 3);
#pragma unroll
            for (int ks = 0; ks < 8; ++ks) {
                float4 u0 = *(const float4*)&Ap[ks * 32];
                float4 u1 = *(const float4*)&Ap[ks * 32 + 4];
                s16x8 w;
                w[0] = (short)f2bf(u0.x); w[1] = (short)f2bf(u0.y);
                w[2] = (short)f2bf(u0.z); w[3] = (short)f2bf(u0.w);
                w[4] = (short)f2bf(u1.x); w[5] = (short)f2bf(u1.y);
                w[6] = (short)f2bf(u1.z); w[7] = (short)f2bf(u1.w);
                af[ks] = w;
            }
        }

#pragma unroll
        for (int px = 0; px < 4; ++px) {
            int bn = px * NCOLS;
            if (px) __syncthreads();            // previous phase done reading Bs
            // stage this phase's B panel (128 rows x 256 k)
#pragma unroll
            for (int p = 0; p < 8; ++p) {
                int idx = p * 512 + tid;
                int n = idx >> 5;
                int kc = (idx & 31) << 3;
                *(s16x8*)&Bs[n][kc] = *(const s16x8*)&Bt[(size_t)(bn + n) * KK + kc];
            }
            __syncthreads();
            f32x4 acc[NT] = {};
#pragma unroll
            for (int nt = 0; nt < NT; ++nt)
#pragma unroll
                for (int ks = 0; ks < 8; ++ks) {
                    s16x8 bfr = *(const s16x8*)&Bs[nt * 16 + l15][ks * 32 + (l4 << 3)];
                    acc[nt] = __builtin_amdgcn_mfma_f32_16x16x32_bf16(af[ks], bfr, acc[nt], 0, 0, 0);
                }
            // epilogue: C + fused attn logits for heads px*2, px*2+1
#pragma unroll
            for (int h = 0; h < 2; ++h) {
                int head = px * 2 + h;
                float asv[4], adv[4];
#pragma unroll
                for (int t = 0; t < 4; ++t) {
                    asv[t] = att_s[head * 64 + t * 16 + l15];
                    adv[t] = att_d[head * 64 + t * 16 + l15];
                }
#pragma unroll
                for (int j = 0; j < 4; ++j) {
                    int r = mbase + (l4 << 2) + j;
                    float ps = 0.f, pd = 0.f;
#pragma unroll
                    for (int t = 0; t < 4; ++t) {
                        float v = acc[h * 4 + t][j];
                        ps += v * asv[t];
                        pd += v * adv[t];
                    }
#pragma unroll
                    for (int off = 1; off < 16; off <<= 1) {
                        ps += __shfl_xor(ps, off);
                        pd += __shfl_xor(pd, off);
                    }
                    if (r < M) {
                        if (l15 == 0) {
                            as_[(size_t)r * 8 + head] = ps;
                            ad_[(size_t)r * 8 + head] = pd;
                        }
#pragma unroll
                        for (int t = 0; t < 4; ++t)
                            C[(size_t)r * Ntot + head * 64 + t * 16 + l15] = f2bf(acc[h * 4 + t][j]);
                    }
                }
            }
        }
        return;
    }
    // ---- CSR scatter tail ----
    __shared__ int s_is64;
    if (threadIdx.x < 64) {
        int v = ebuf[2 * threadIdx.x + 1];      // odd slots zero => int64
        unsigned long long bl = __ballot(v != 0);
        if (threadIdx.x == 0) s_is64 = (bl == 0ull) ? 1 : 0;
    }
    __syncthreads();
    int is64 = s_is64;
    int i = (g - nGemm) * 512 + threadIdx.x;
    if (i >= E + Nn) return;
    int s, d;
    if (i < E) {
        s = edge_val(ebuf, i, is64);
        d = edge_val(ebuf, (long long)E + i, is64);
    } else {
        s = i - E; d = s;                       // self-loop
    }
    int pos = atomicAdd(&counts[d], 1);
    if (pos < CAP) csr[(size_t)d * CAP + pos] = s;
}

// ---------- layer-2 GEMM (pure B-resident, whole W2t in LDS, one barrier) ----------
__global__ __launch_bounds__(512) void gemm2_bres(
        const ushort* __restrict__ A, const ushort* __restrict__ Bt, ushort* __restrict__ C,
        const float* __restrict__ att_s, const float* __restrict__ att_d,
        float* __restrict__ as_, float* __restrict__ ad_, int M) {
    constexpr int KK = 512, NCOLS = 64, NT = 4;
    __shared__ __align__(16) ushort Bs[NCOLS][KK + 8];
    int tid = threadIdx.x;
    int wid = tid >> 6, lane = tid & 63;
    int l15 = lane & 15, l4 = lane >> 4;

    // stage whole W2t (64 x 512)
#pragma unroll
    for (int p = 0; p < NCOLS * KK / (8 * 512); ++p) {
        int idx = p * 512 + tid;
        int n = idx >> 6;
        int kc = (idx & 63) << 3;
        *(s16x8*)&Bs[n][kc] = *(const s16x8*)&Bt[(size_t)n * KK + kc];
    }

    int mbase = blockIdx.y * 128 + wid * 16;
    int rowA = mbase + l15; if (rowA >= M) rowA = M - 1;
    const ushort* Ap = A + (size_t)rowA * KK + (l4 << 3);
    s16x8 af[16];
#pragma unroll
    for (int ks = 0; ks < 16; ++ks) af[ks] = *(const s16x8*)&Ap[ks * 32];

    __syncthreads();                            // the only barrier

    f32x4 acc[NT] = {};
#pragma unroll
    for (int nt = 0; nt < NT; ++nt)
#pragma unroll
        for (int ks = 0; ks < 16; ++ks) {
            s16x8 bfr = *(const s16x8*)&Bs[nt * 16 + l15][ks * 32 + (l4 << 3)];
            acc[nt] = __builtin_amdgcn_mfma_f32_16x16x32_bf16(af[ks], bfr, acc[nt], 0, 0, 0);
        }

    float asv[NT], adv[NT];
#pragma unroll
    for (int t = 0; t < NT; ++t) {
        asv[t] = att_s[t * 16 + l15];
        adv[t] = att_d[t * 16 + l15];
    }
#pragma unroll
    for (int j = 0; j < 4; ++j) {
        int r = mbase + (l4 << 2) + j;
        float ps = 0.f, pd = 0.f;
#pragma unroll
        for (int t = 0; t < NT; ++t) {
            float v = acc[t][j];
            ps += v * asv[t];
            pd += v * adv[t];
        }
#pragma unroll
        for (int off = 1; off < 16; off <<= 1) {
            ps += __shfl_xor(ps, off);
            pd += __shfl_xor(pd, off);
        }
        if (r < M) {
            if (l15 == 0) { as_[r] = ps; ad_[r] = pd; }
#pragma unroll
            for (int t = 0; t < NT; ++t)
                C[((size_t)r << 6) + t * 16 + l15] = f2bf(acc[t][j]);
        }
    }
}

// ---------- layer-1 fused softmax+aggregate: one wave per node, no barriers ----------
__global__ __launch_bounds__(256) void gat_fused_l1(
        const ushort* __restrict__ h, const float* __restrict__ as_,
        const float* __restrict__ ad_, const int* __restrict__ counts,
        const int* __restrict__ csr, const float* __restrict__ bias,
        ushort* __restrict__ out1, int N) {
    int n = (blockIdx.x * 256 + threadIdx.x) >> 6;
    if (n >= N) return;
    int l = threadIdx.x & 63;
    size_t base = (size_t)n * CAP;
    int deg = counts[n]; deg = deg > CAP ? CAP : deg;

    int hh = l & 7, e0 = l >> 3;
    float adw = ad_[n * 8 + hh];
    float m = -1e30f, s = 0.f;
    for (int k = e0; k < deg; k += 8) {
        int src = csr[base + k];
        float e = as_[src * 8 + hh] + adw;
        e = e > 0.f ? e : NEG_SLOPE * e;
        float mn = fmaxf(m, e);
        s = s * __expf(m - mn) + __expf(e - mn);
        m = mn;
    }
#pragma unroll
    for (int off = 8; off < 64; off <<= 1) {
        float mo = __shfl_xor(m, off), so = __shfl_xor(s, off);
        float mn = fmaxf(m, mo);
        s = s * __expf(m - mn) + so * __expf(mo - mn);
        m = mn;
    }
    float inv = 1.f / (s + 1e-16f);
    int hd = l >> 3;
    float mh   = __shfl(m, hd);
    float invh = __shfl(inv, hd);
    float adh  = __shfl(adw, hd);

    float acc[8] = {};
    int k = 0;
    for (; k + 4 <= deg; k += 4) {
        int s0 = csr[base + k],     s1 = csr[base + k + 1];
        int s2 = csr[base + k + 2], s3 = csr[base + k + 3];
        s16x8 v0 = *(const s16x8*)&h[((size_t)s0 << 9) + (l << 3)];
        s16x8 v1 = *(const s16x8*)&h[((size_t)s1 << 9) + (l << 3)];
        s16x8 v2 = *(const s16x8*)&h[((size_t)s2 << 9) + (l << 3)];
        s16x8 v3 = *(const s16x8*)&h[((size_t)s3 << 9) + (l << 3)];
        float e0v = as_[s0 * 8 + hd] + adh;
        float e1v = as_[s1 * 8 + hd] + adh;
        float e2v = as_[s2 * 8 + hd] + adh;
        float e3v = as_[s3 * 8 + hd] + adh;
        e0v = e0v > 0.f ? e0v : NEG_SLOPE * e0v;
        e1v = e1v > 0.f ? e1v : NEG_SLOPE * e1v;
        e2v = e2v > 0.f ? e2v : NEG_SLOPE * e2v;
        e3v = e3v > 0.f ? e3v : NEG_SLOPE * e3v;
        float a0 = __expf(e0v - mh);
        float a1 = __expf(e1v - mh);
        float a2 = __expf(e2v - mh);
        float a3 = __expf(e3v - mh);
#pragma unroll
        for (int j = 0; j < 8; ++j)
            acc[j] += a0 * bf2f((ushort)v0[j]) + a1 * bf2f((ushort)v1[j])
                    + a2 * bf2f((ushort)v2[j]) + a3 * bf2f((ushort)v3[j]);
    }
    for (; k < deg; ++k) {
        int s0 = csr[base + k];
        s16x8 v0 = *(const s16x8*)&h[((size_t)s0 << 9) + (l << 3)];
        float e0v = as_[s0 * 8 + hd] + adh;
        e0v = e0v > 0.f ? e0v : NEG_SLOPE * e0v;
        float a0 = __expf(e0v - mh);
#pragma unroll
        for (int j = 0; j < 8; ++j) acc[j] += a0 * bf2f((ushort)v0[j]);
    }
    float4 b0 = *(const float4*)&bias[l * 8];
    float4 b1 = *(const float4*)&bias[l * 8 + 4];
    s16x8 w;
    w[0] = f2bf(fmaxf(acc[0] * invh + b0.x, 0.f));
    w[1] = f2bf(fmaxf(acc[1] * invh + b0.y, 0.f));
    w[2] = f2bf(fmaxf(acc[2] * invh + b0.z, 0.f));
    w[3] = f2bf(fmaxf(acc[3] * invh + b0.w, 0.f));
    w[4] = f2bf(fmaxf(acc[4] * invh + b1.x, 0.f));
    w[5] = f2bf(fmaxf(acc[5] * invh + b1.y, 0.f));
    w[6] = f2bf(fmaxf(acc[6] * invh + b1.z, 0.f));
    w[7] = f2bf(fmaxf(acc[7] * invh + b1.w, 0.f));
    *(s16x8*)&out1[((size_t)n << 9) + (l << 3)] = w;
}

// ---------- layer-2 fused: wave per node; quarter-wave per edge (128B bf16 row) ----------
__global__ __launch_bounds__(256) void gat_fused_l2(
        const ushort* __restrict__ h, const float* __restrict__ as_,
        const float* __restrict__ ad_, const int* __restrict__ counts,
        const int* __restrict__ csr, const float* __restrict__ bias,
        float* __restrict__ out, int N) {
    int n = (blockIdx.x * 256 + threadIdx.x) >> 6;
    if (n >= N) return;
    int l = threadIdx.x & 63;
    size_t base = (size_t)n * CAP;
    int deg = counts[n]; deg = deg > CAP ? CAP : deg;
    float adv = ad_[n];

    float m = -1e30f, s = 0.f;
    for (int k = l; k < deg; k += 64) {
        float e = as_[csr[base + k]] + adv;
        e = e > 0.f ? e : NEG_SLOPE * e;
        float mn = fmaxf(m, e);
        s = s * __expf(m - mn) + __expf(e - mn);
        m = mn;
    }
#pragma unroll
    for (int off = 1; off < 64; off <<= 1) {
        float mo = __shfl_xor(m, off), so = __shfl_xor(s, off);
        float mn = fmaxf(m, mo);
        s = s * __expf(m - mn) + so * __expf(mo - mn);
        m = mn;
    }
    float inv = 1.f / (s + 1e-16f);

    int q = l >> 4, c4 = l & 15;
    float a0 = 0.f, a1 = 0.f, a2 = 0.f, a3 = 0.f;
    int k = q;
    for (; k + 12 < deg; k += 16) {
        int sA = csr[base + k],     sB = csr[base + k + 4];
        int sC = csr[base + k + 8], sD = csr[base + k + 12];
        s16x4 vA = *(const s16x4*)&h[((size_t)sA << 6) + (c4 << 2)];
        s16x4 vB = *(const s16x4*)&h[((size_t)sB << 6) + (c4 << 2)];
        s16x4 vC = *(const s16x4*)&h[((size_t)sC << 6) + (c4 << 2)];
        s16x4 vD = *(const s16x4*)&h[((size_t)sD << 6) + (c4 << 2)];
        float eA = as_[sA] + adv, eB = as_[sB] + adv;
        float eC = as_[sC] + adv, eD = as_[sD] + adv;
        eA = eA > 0.f ? eA : NEG_SLOPE * eA;
        eB = eB > 0.f ? eB : NEG_SLOPE * eB;
        eC = eC > 0.f ? eC : NEG_SLOPE * eC;
        eD = eD > 0.f ? eD : NEG_SLOPE * eD;
        float aA = __expf(eA - m), aB = __expf(eB - m);
        float aC = __expf(eC - m), aD = __expf(eD - m);
        a0 += aA * bf2f((ushort)vA[0]) + aB * bf2f((ushort)vB[0])
            + aC * bf2f((ushort)vC[0]) + aD * bf2f((ushort)vD[0]);
        a1 += aA * bf2f((ushort)vA[1]) + aB * bf2f((ushort)vB[1])
            + aC * bf2f((ushort)vC[1]) + aD * bf2f((ushort)vD[1]);
        a2 += aA * bf2f((ushort)vA[2]) + aB * bf2f((ushort)vB[2])
            + aC * bf2f((ushort)vC[2]) + aD * bf2f((ushort)vD[2]);
        a3 += aA * bf2f((ushort)vA[3]) + aB * bf2f((ushort)vB[3])
            + aC * bf2f((ushort)vC[3]) + aD * bf2f((ushort)vD[3]);
    }
    for (; k < deg; k += 4) {
        int sA = csr[base + k];
        s16x4 vA = *(const s16x4*)&h[((size_t)sA << 6) + (c4 << 2)];
        float eA = as_[sA] + adv;
        eA = eA > 0.f ? eA : NEG_SLOPE * eA;
        float aA = __expf(eA - m);
        a0 += aA * bf2f((ushort)vA[0]);
        a1 += aA * bf2f((ushort)vA[1]);
        a2 += aA * bf2f((ushort)vA[2]);
        a3 += aA * bf2f((ushort)vA[3]);
    }
    a0 += __shfl_xor(a0, 16); a0 += __shfl_xor(a0, 32);
    a1 += __shfl_xor(a1, 16); a1 += __shfl_xor(a1, 32);
    a2 += __shfl_xor(a2, 16); a2 += __shfl_xor(a2, 32);
    a3 += __shfl_xor(a3, 16); a3 += __shfl_xor(a3, 32);
    if (q == 0) {
        float4 bv = *(const float4*)&bias[c4 << 2];
        float4 r;
        r.x = a0 * inv + bv.x; r.y = a1 * inv + bv.y;
        r.z = a2 * inv + bv.z; r.w = a3 * inv + bv.w;
        *(float4*)&out[((size_t)n << 6) + (c4 << 2)] = r;
    }
}

// ---------- launch ----------
extern "C" void kernel_launch(void* const* d_in, const int* in_sizes, int n_in,
                              void* d_out, int out_size, void* d_ws, size_t ws_size,
                              hipStream_t stream) {
    const float* x    = (const float*)d_in[0];
    const int*   ebuf = (const int*)d_in[1];
    const float* W1   = (const float*)d_in[2];
    const float* aS1  = (const float*)d_in[3];
    const float* aD1  = (const float*)d_in[4];
    const float* b1   = (const float*)d_in[5];
    const float* W2   = (const float*)d_in[6];
    const float* aS2  = (const float*)d_in[7];
    const float* aD2  = (const float*)d_in[8];
    const float* b2   = (const float*)d_in[9];
    float* out = (float*)d_out;

    const int F_in = 256, H1 = 8, HC1 = 512, C2 = 64;
    int N = in_sizes[0] / F_in;   // 50000
    int E = in_sizes[1] / 2;      // 800000

    char* ws = (char*)d_ws;
    size_t off = 0;
    auto alloc = [&](size_t bytes) -> void* {
        void* p = ws + off;
        off = (off + bytes + 255) & ~(size_t)255;
        return p;
    };
    ushort* h1b    = (ushort*)alloc((size_t)N * HC1 * 2);
    ushort* out1b  = (ushort*)alloc((size_t)N * HC1 * 2);
    float* as1     = (float*)alloc((size_t)N * H1 * 4);
    float* ad1     = (float*)alloc((size_t)N * H1 * 4);
    float* as2     = (float*)alloc((size_t)N * 4);
    float* ad2     = (float*)alloc((size_t)N * 4);
    int*   counts  = (int*)alloc((size_t)N * 4);
    int*   csr     = (int*)alloc((size_t)N * CAP * 4);
    ushort* W1t    = (ushort*)alloc((size_t)F_in * HC1 * 2);
    ushort* W2t    = (ushort*)alloc((size_t)HC1 * C2 * 2);
    ushort* h2b    = h1b;    // h1b dead after gat_fused_l1

    int nbW1 = (F_in * HC1 + 255) >> 8;
    int nbW2 = (HC1 * C2 + 255) >> 8;
    int nbZ  = (N + 255) >> 8;

    // 1) prep: W transposes + counts zeroing
    prep_k<<<nbW1 + nbW2 + nbZ, 256, 0, stream>>>(
        W1, W1t, F_in, HC1, W2, W2t, HC1, C2, counts, N, nbW1, nbW2);

    // 2) layer-1 GEMM (4-phase B-resident, A once, 2 blocks/CU) + scatter tail
    {
        int nGemm = (N + 127) / 128;           // 391
        int nScatter = (E + N + 511) / 512;    // 1660
        gemm1_scatter<<<nGemm + nScatter, 512, 0, stream>>>(
            x, W1t, h1b, aS1, aD1, as1, ad1, N, HC1, nGemm,
            ebuf, E, N, counts, csr);
    }

    // 3) layer-1 fused softmax+aggregate
    gat_fused_l1<<<(N + 3) / 4, 256, 0, stream>>>(h1b, as1, ad1, counts, csr, b1, out1b, N);

    // 4) layer-2 GEMM (whole W2t in LDS, one barrier)
    {
        dim3 g(1, (N + 127) / 128);
        gemm2_bres<<<g, 512, 0, stream>>>(out1b, W2t, h2b, aS2, aD2, as2, ad2, N);
    }

    // 5) layer-2 fused softmax+aggregate
    gat_fused_l2<<<(N + 3) / 4, 256, 0, stream>>>(h2b, as2, ad2, counts, csr, b2, out, N);
}

// Round 17
// 249.576 us; speedup vs baseline: 1.3324x; 1.0444x over previous
//
#include <hip/hip_runtime.h>
#include <hip/hip_bf16.h>
#include <math.h>
#include <type_traits>

#define NEG_SLOPE 0.2f
#define CAP 64           // fixed CSR row capacity (max in-degree+1; Poisson(16) -> P(>=64) ~ 1e-13)

typedef float f32x4 __attribute__((ext_vector_type(4)));
typedef short s16x8 __attribute__((ext_vector_type(8)));
typedef short s16x4 __attribute__((ext_vector_type(4)));

__device__ __forceinline__ float bf2f(ushort s) {
    union { unsigned u; float f; } cv; cv.u = ((unsigned)s) << 16;
    return cv.f;
}
__device__ __forceinline__ ushort f2bf(float f) {
    __hip_bfloat16 b = __float2bfloat16(f);
    union { __hip_bfloat16 b; ushort u; } cv; cv.b = b;
    return cv.u;
}

// ---------- edge dtype handling (int32 vs int64 little-endian) ----------
__device__ __forceinline__ int edge_val(const int* e, long long i, int is64) {
    return is64 ? e[(size_t)(2 * i)] : e[(size_t)i];
}

// ---------- prep: W1t | W2t transposes only ----------
__global__ __launch_bounds__(256) void prep_k(
        const float* __restrict__ W1, ushort* __restrict__ W1t, int K1, int N1,
        const float* __restrict__ W2, ushort* __restrict__ W2t, int K2, int N2,
        int nbW1) {
    int b = blockIdx.x, tid = threadIdx.x;
    if (b < nbW1) {
        int idx = b * 256 + tid;
        if (idx < K1 * N1) {
            int k = idx & (K1 - 1), n = idx / K1;
            W1t[(size_t)n * K1 + k] = f2bf(W1[(size_t)k * N1 + n]);
        }
        return;
    }
    b -= nbW1;
    int idx = b * 256 + tid;
    if (idx < K2 * N2) {
        int k = idx & (K2 - 1), n = idx / K2;
        W2t[(size_t)n * K2 + k] = f2bf(W2[(size_t)k * N2 + n]);
    }
}

// ---------- layer-1 GEMM: 4-phase B-resident (A loaded ONCE; 2 blocks/CU) + scatter tail ----
__global__ __launch_bounds__(512) void gemm1_scatter(
        const float* __restrict__ A, const ushort* __restrict__ Bt,
        ushort* __restrict__ C, const float* __restrict__ att_s,
        const float* __restrict__ att_d, float* __restrict__ as_,
        float* __restrict__ ad_, int M, int Ntot, int nGemm,
        const int* __restrict__ ebuf, int E, int Nn,
        int* __restrict__ counts, int* __restrict__ csr) {
    int g = blockIdx.x;
    if (g < nGemm) {
        constexpr int KK = 256, NCOLS = 128, NT = 8;
        __shared__ __align__(16) ushort Bs[NCOLS][KK + 8];
        int tid = threadIdx.x;
        int wid = tid >> 6, lane = tid & 63;
        int l15 = lane & 15, l4 = lane >> 4;
        int mbase = g * 128 + wid * 16;
        int rowA = mbase + l15; if (rowA >= M) rowA = M - 1;

        // stream A row slice once (fp32 -> bf16 in registers)
        s16x8 af[8];
        {
            const float* Ap = A + (size_t)rowA * KK + (l4 << 3);
#pragma unroll
            for (int ks = 0; ks < 8; ++ks) {
                float4 u0 = *(const float4*)&Ap[ks * 32];
                float4 u1 = *(const float4*)&Ap[ks * 32 + 4];
                s16x8 w;
                w[0] = (short)f2bf(u0.x); w[1] = (short)f2bf(u0.y);
                w[2] = (short)f2bf(u0.z); w[3] = (short)f2bf(u0.w);
                w[4] = (short)f2bf(u1.x); w[5] = (short)f2bf(u1.y);
                w[6] = (short)f2bf(u1.z); w[7] = (short)f2bf(u1.w);
                af[ks] = w;
            }
        }

#pragma unroll
        for (int px = 0; px < 4; ++px) {
            int bn = px * NCOLS;
            if (px) __syncthreads();            // previous phase done reading Bs
#pragma unroll
            for (int p = 0; p < 8; ++p) {
                int idx = p * 512 + tid;
                int n = idx >> 5;
                int kc = (idx & 31) << 3;
                *(s16x8*)&Bs[n][kc] = *(const s16x8*)&Bt[(size_t)(bn + n) * KK + kc];
            }
            __syncthreads();
            f32x4 acc[NT] = {};
#pragma unroll
            for (int nt = 0; nt < NT; ++nt)
#pragma unroll
                for (int ks = 0; ks < 8; ++ks) {
                    s16x8 bfr = *(const s16x8*)&Bs[nt * 16 + l15][ks * 32 + (l4 << 3)];
                    acc[nt] = __builtin_amdgcn_mfma_f32_16x16x32_bf16(af[ks], bfr, acc[nt], 0, 0, 0);
                }
#pragma unroll
            for (int h = 0; h < 2; ++h) {
                int head = px * 2 + h;
                float asv[4], adv[4];
#pragma unroll
                for (int t = 0; t < 4; ++t) {
                    asv[t] = att_s[head * 64 + t * 16 + l15];
                    adv[t] = att_d[head * 64 + t * 16 + l15];
                }
#pragma unroll
                for (int j = 0; j < 4; ++j) {
                    int r = mbase + (l4 << 2) + j;
                    float ps = 0.f, pd = 0.f;
#pragma unroll
                    for (int t = 0; t < 4; ++t) {
                        float v = acc[h * 4 + t][j];
                        ps += v * asv[t];
                        pd += v * adv[t];
                    }
#pragma unroll
                    for (int off = 1; off < 16; off <<= 1) {
                        ps += __shfl_xor(ps, off);
                        pd += __shfl_xor(pd, off);
                    }
                    if (r < M) {
                        if (l15 == 0) {
                            as_[(size_t)r * 8 + head] = ps;
                            ad_[(size_t)r * 8 + head] = pd;
                        }
#pragma unroll
                        for (int t = 0; t < 4; ++t)
                            C[(size_t)r * Ntot + head * 64 + t * 16 + l15] = f2bf(acc[h * 4 + t][j]);
                    }
                }
            }
        }
        return;
    }
    // ---- CSR scatter tail ----
    __shared__ int s_is64;
    if (threadIdx.x < 64) {
        int v = ebuf[2 * threadIdx.x + 1];      // odd slots zero => int64
        unsigned long long bl = __ballot(v != 0);
        if (threadIdx.x == 0) s_is64 = (bl == 0ull) ? 1 : 0;
    }
    __syncthreads();
    int is64 = s_is64;
    int i = (g - nGemm) * 512 + threadIdx.x;
    if (i >= E + Nn) return;
    int s, d;
    if (i < E) {
        s = edge_val(ebuf, i, is64);
        d = edge_val(ebuf, (long long)E + i, is64);
    } else {
        s = i - E; d = s;                       // self-loop
    }
    int pos = atomicAdd(&counts[d], 1);
    if (pos < CAP) csr[(size_t)d * CAP + pos] = s;
}

// ---------- layer-2 GEMM (pure B-resident, whole W2t in LDS, one barrier) ----------
__global__ __launch_bounds__(512) void gemm2_bres(
        const ushort* __restrict__ A, const ushort* __restrict__ Bt, ushort* __restrict__ C,
        const float* __restrict__ att_s, const float* __restrict__ att_d,
        float* __restrict__ as_, float* __restrict__ ad_, int M) {
    constexpr int KK = 512, NCOLS = 64, NT = 4;
    __shared__ __align__(16) ushort Bs[NCOLS][KK + 8];
    int tid = threadIdx.x;
    int wid = tid >> 6, lane = tid & 63;
    int l15 = lane & 15, l4 = lane >> 4;

#pragma unroll
    for (int p = 0; p < NCOLS * KK / (8 * 512); ++p) {
        int idx = p * 512 + tid;
        int n = idx >> 6;
        int kc = (idx & 63) << 3;
        *(s16x8*)&Bs[n][kc] = *(const s16x8*)&Bt[(size_t)n * KK + kc];
    }

    int mbase = blockIdx.y * 128 + wid * 16;
    int rowA = mbase + l15; if (rowA >= M) rowA = M - 1;
    const ushort* Ap = A + (size_t)rowA * KK + (l4 << 3);
    s16x8 af[16];
#pragma unroll
    for (int ks = 0; ks < 16; ++ks) af[ks] = *(const s16x8*)&Ap[ks * 32];

    __syncthreads();                            // the only barrier

    f32x4 acc[NT] = {};
#pragma unroll
    for (int nt = 0; nt < NT; ++nt)
#pragma unroll
        for (int ks = 0; ks < 16; ++ks) {
            s16x8 bfr = *(const s16x8*)&Bs[nt * 16 + l15][ks * 32 + (l4 << 3)];
            acc[nt] = __builtin_amdgcn_mfma_f32_16x16x32_bf16(af[ks], bfr, acc[nt], 0, 0, 0);
        }

    float asv[NT], adv[NT];
#pragma unroll
    for (int t = 0; t < NT; ++t) {
        asv[t] = att_s[t * 16 + l15];
        adv[t] = att_d[t * 16 + l15];
    }
#pragma unroll
    for (int j = 0; j < 4; ++j) {
        int r = mbase + (l4 << 2) + j;
        float ps = 0.f, pd = 0.f;
#pragma unroll
        for (int t = 0; t < NT; ++t) {
            float v = acc[t][j];
            ps += v * asv[t];
            pd += v * adv[t];
        }
#pragma unroll
        for (int off = 1; off < 16; off <<= 1) {
            ps += __shfl_xor(ps, off);
            pd += __shfl_xor(pd, off);
        }
        if (r < M) {
            if (l15 == 0) { as_[r] = ps; ad_[r] = pd; }
#pragma unroll
            for (int t = 0; t < NT; ++t)
                C[((size_t)r << 6) + t * 16 + l15] = f2bf(acc[t][j]);
        }
    }
}

// ---------- layer-1 fused softmax+aggregate: one wave per node (round-15 form) ----------
__global__ __launch_bounds__(256) void gat_fused_l1(
        const ushort* __restrict__ h, const float* __restrict__ as_,
        const float* __restrict__ ad_, const int* __restrict__ counts,
        const int* __restrict__ csr, const float* __restrict__ bias,
        ushort* __restrict__ out1, int N) {
    int n = (blockIdx.x * 256 + threadIdx.x) >> 6;
    if (n >= N) return;
    int l = threadIdx.x & 63;
    size_t base = (size_t)n * CAP;
    int deg = counts[n]; deg = deg > CAP ? CAP : deg;

    int hh = l & 7, e0 = l >> 3;
    float adw = ad_[n * 8 + hh];
    float m = -1e30f, s = 0.f;
    for (int k = e0; k < deg; k += 8) {
        int src = csr[base + k];
        float e = as_[src * 8 + hh] + adw;
        e = e > 0.f ? e : NEG_SLOPE * e;
        float mn = fmaxf(m, e);
        s = s * __expf(m - mn) + __expf(e - mn);
        m = mn;
    }
#pragma unroll
    for (int off = 8; off < 64; off <<= 1) {
        float mo = __shfl_xor(m, off), so = __shfl_xor(s, off);
        float mn = fmaxf(m, mo);
        s = s * __expf(m - mn) + so * __expf(mo - mn);
        m = mn;
    }
    float inv = 1.f / (s + 1e-16f);
    int hd = l >> 3;
    float mh   = __shfl(m, hd);
    float invh = __shfl(inv, hd);
    float adh  = __shfl(adw, hd);

    float acc[8] = {};
    int k = 0;
    for (; k + 4 <= deg; k += 4) {
        int s0 = csr[base + k],     s1 = csr[base + k + 1];
        int s2 = csr[base + k + 2], s3 = csr[base + k + 3];
        s16x8 v0 = *(const s16x8*)&h[((size_t)s0 << 9) + (l << 3)];
        s16x8 v1 = *(const s16x8*)&h[((size_t)s1 << 9) + (l << 3)];
        s16x8 v2 = *(const s16x8*)&h[((size_t)s2 << 9) + (l << 3)];
        s16x8 v3 = *(const s16x8*)&h[((size_t)s3 << 9) + (l << 3)];
        float e0v = as_[s0 * 8 + hd] + adh;
        float e1v = as_[s1 * 8 + hd] + adh;
        float e2v = as_[s2 * 8 + hd] + adh;
        float e3v = as_[s3 * 8 + hd] + adh;
        e0v = e0v > 0.f ? e0v : NEG_SLOPE * e0v;
        e1v = e1v > 0.f ? e1v : NEG_SLOPE * e1v;
        e2v = e2v > 0.f ? e2v : NEG_SLOPE * e2v;
        e3v = e3v > 0.f ? e3v : NEG_SLOPE * e3v;
        float a0 = __expf(e0v - mh);
        float a1 = __expf(e1v - mh);
        float a2 = __expf(e2v - mh);
        float a3 = __expf(e3v - mh);
#pragma unroll
        for (int j = 0; j < 8; ++j)
            acc[j] += a0 * bf2f((ushort)v0[j]) + a1 * bf2f((ushort)v1[j])
                    + a2 * bf2f((ushort)v2[j]) + a3 * bf2f((ushort)v3[j]);
    }
    for (; k < deg; ++k) {
        int s0 = csr[base + k];
        s16x8 v0 = *(const s16x8*)&h[((size_t)s0 << 9) + (l << 3)];
        float e0v = as_[s0 * 8 + hd] + adh;
        e0v = e0v > 0.f ? e0v : NEG_SLOPE * e0v;
        float a0 = __expf(e0v - mh);
#pragma unroll
        for (int j = 0; j < 8; ++j) acc[j] += a0 * bf2f((ushort)v0[j]);
    }
    float4 b0 = *(const float4*)&bias[l * 8];
    float4 b1 = *(const float4*)&bias[l * 8 + 4];
    s16x8 w;
    w[0] = f2bf(fmaxf(acc[0] * invh + b0.x, 0.f));
    w[1] = f2bf(fmaxf(acc[1] * invh + b0.y, 0.f));
    w[2] = f2bf(fmaxf(acc[2] * invh + b0.z, 0.f));
    w[3] = f2bf(fmaxf(acc[3] * invh + b0.w, 0.f));
    w[4] = f2bf(fmaxf(acc[4] * invh + b1.x, 0.f));
    w[5] = f2bf(fmaxf(acc[5] * invh + b1.y, 0.f));
    w[6] = f2bf(fmaxf(acc[6] * invh + b1.z, 0.f));
    w[7] = f2bf(fmaxf(acc[7] * invh + b1.w, 0.f));
    *(s16x8*)&out1[((size_t)n << 9) + (l << 3)] = w;
}

// ---------- layer-2 fused: meta-free gather with WAVE-UNIFORM loop trips ----------
// deg <= 64: lane l owns edge l (src + unnormalized alpha in registers). The gather
// loop runs ceil(deg/16) iterations on ALL lanes (so every __shfl executes with the
// full wave active — ds_bpermute from inactive lanes returns 0, the round-16 bug).
// Invalid edges: alpha == 0 (lanes >= deg) and their row loads are predicated off.
__global__ __launch_bounds__(256) void gat_fused_l2(
        const ushort* __restrict__ h, const float* __restrict__ as_,
        const float* __restrict__ ad_, const int* __restrict__ counts,
        const int* __restrict__ csr, const float* __restrict__ bias,
        float* __restrict__ out, int N) {
    int n = (blockIdx.x * 256 + threadIdx.x) >> 6;
    if (n >= N) return;                         // uniform per wave
    int l = threadIdx.x & 63;
    size_t base = (size_t)n * CAP;
    int deg = counts[n]; deg = deg > CAP ? CAP : deg;
    float adv = ad_[n];

    int srcA = csr[base + (l < deg ? l : 0)];   // one coalesced 64x4B load
    float e = as_[srcA] + adv;
    e = e > 0.f ? e : NEG_SLOPE * e;
    if (l >= deg) e = -1e30f;
    float m = e;
#pragma unroll
    for (int off = 1; off < 64; off <<= 1) m = fmaxf(m, __shfl_xor(m, off));
    float al = (l < deg) ? __expf(e - m) : 0.f;
    float s = al;
#pragma unroll
    for (int off = 1; off < 64; off <<= 1) s += __shfl_xor(s, off);
    float inv = 1.f / (s + 1e-16f);

    // gather: quarter-wave q per edge; uniform iteration count; predicated loads
    int q = l >> 4, c4 = l & 15;
    float a0 = 0.f, a1 = 0.f, a2 = 0.f, a3 = 0.f;
    int nIter = (deg + 15) >> 4;
    for (int i = 0; i < nIter; ++i) {
        int kA = (i << 4) + q;                  // kA..kD <= 63 always
        int kB = kA + 4, kC = kA + 8, kD = kA + 12;
        int sA = __shfl(srcA, kA), sB = __shfl(srcA, kB);
        int sC = __shfl(srcA, kC), sD = __shfl(srcA, kD);
        float aA = __shfl(al, kA), aB = __shfl(al, kB);
        float aC = __shfl(al, kC), aD = __shfl(al, kD);
        s16x4 vA = {}, vB = {}, vC = {}, vD = {};
        if (kA < deg) vA = *(const s16x4*)&h[((size_t)sA << 6) + (c4 << 2)];
        if (kB < deg) vB = *(const s16x4*)&h[((size_t)sB << 6) + (c4 << 2)];
        if (kC < deg) vC = *(const s16x4*)&h[((size_t)sC << 6) + (c4 << 2)];
        if (kD < deg) vD = *(const s16x4*)&h[((size_t)sD << 6) + (c4 << 2)];
        a0 += aA * bf2f((ushort)vA[0]) + aB * bf2f((ushort)vB[0])
            + aC * bf2f((ushort)vC[0]) + aD * bf2f((ushort)vD[0]);
        a1 += aA * bf2f((ushort)vA[1]) + aB * bf2f((ushort)vB[1])
            + aC * bf2f((ushort)vC[1]) + aD * bf2f((ushort)vD[1]);
        a2 += aA * bf2f((ushort)vA[2]) + aB * bf2f((ushort)vB[2])
            + aC * bf2f((ushort)vC[2]) + aD * bf2f((ushort)vD[2]);
        a3 += aA * bf2f((ushort)vA[3]) + aB * bf2f((ushort)vB[3])
            + aC * bf2f((ushort)vC[3]) + aD * bf2f((ushort)vD[3]);
    }
    a0 += __shfl_xor(a0, 16); a0 += __shfl_xor(a0, 32);
    a1 += __shfl_xor(a1, 16); a1 += __shfl_xor(a1, 32);
    a2 += __shfl_xor(a2, 16); a2 += __shfl_xor(a2, 32);
    a3 += __shfl_xor(a3, 16); a3 += __shfl_xor(a3, 32);
    if (q == 0) {
        float4 bv = *(const float4*)&bias[c4 << 2];
        float4 r;
        r.x = a0 * inv + bv.x; r.y = a1 * inv + bv.y;
        r.z = a2 * inv + bv.z; r.w = a3 * inv + bv.w;
        *(float4*)&out[((size_t)n << 6) + (c4 << 2)] = r;
    }
}

// ---------- launch ----------
extern "C" void kernel_launch(void* const* d_in, const int* in_sizes, int n_in,
                              void* d_out, int out_size, void* d_ws, size_t ws_size,
                              hipStream_t stream) {
    const float* x    = (const float*)d_in[0];
    const int*   ebuf = (const int*)d_in[1];
    const float* W1   = (const float*)d_in[2];
    const float* aS1  = (const float*)d_in[3];
    const float* aD1  = (const float*)d_in[4];
    const float* b1   = (const float*)d_in[5];
    const float* W2   = (const float*)d_in[6];
    const float* aS2  = (const float*)d_in[7];
    const float* aD2  = (const float*)d_in[8];
    const float* b2   = (const float*)d_in[9];
    float* out = (float*)d_out;

    const int F_in = 256, H1 = 8, HC1 = 512, C2 = 64;
    int N = in_sizes[0] / F_in;   // 50000
    int E = in_sizes[1] / 2;      // 800000

    char* ws = (char*)d_ws;
    size_t off = 0;
    auto alloc = [&](size_t bytes) -> void* {
        void* p = ws + off;
        off = (off + bytes + 255) & ~(size_t)255;
        return p;
    };
    ushort* h1b    = (ushort*)alloc((size_t)N * HC1 * 2);
    ushort* out1b  = (ushort*)alloc((size_t)N * HC1 * 2);
    float* as1     = (float*)alloc((size_t)N * H1 * 4);
    float* ad1     = (float*)alloc((size_t)N * H1 * 4);
    float* as2     = (float*)alloc((size_t)N * 4);
    float* ad2     = (float*)alloc((size_t)N * 4);
    int*   counts  = (int*)alloc((size_t)N * 4);
    int*   csr     = (int*)alloc((size_t)N * CAP * 4);
    ushort* W1t    = (ushort*)alloc((size_t)F_in * HC1 * 2);
    ushort* W2t    = (ushort*)alloc((size_t)HC1 * C2 * 2);
    ushort* h2b    = h1b;    // h1b dead after gat_fused_l1

    int nbW1 = (F_in * HC1 + 255) >> 8;
    int nbW2 = (HC1 * C2 + 255) >> 8;

    // 0) zero per-node counters
    hipMemsetAsync(counts, 0, (size_t)N * 4, stream);

    // 1) prep: W transposes
    prep_k<<<nbW1 + nbW2, 256, 0, stream>>>(W1, W1t, F_in, HC1, W2, W2t, HC1, C2, nbW1);

    // 2) layer-1 GEMM (4-phase B-resident, A once, 2 blocks/CU) + scatter tail
    {
        int nGemm = (N + 127) / 128;           // 391
        int nScatter = (E + N + 511) / 512;    // 1660
        gemm1_scatter<<<nGemm + nScatter, 512, 0, stream>>>(
            x, W1t, h1b, aS1, aD1, as1, ad1, N, HC1, nGemm,
            ebuf, E, N, counts, csr);
    }

    // 3) layer-1 fused softmax+aggregate
    gat_fused_l1<<<(N + 3) / 4, 256, 0, stream>>>(h1b, as1, ad1, counts, csr, b1, out1b, N);

    // 4) layer-2 GEMM (whole W2t in LDS, one barrier)
    {
        dim3 g(1, (N + 127) / 128);
        gemm2_bres<<<g, 512, 0, stream>>>(out1b, W2t, h2b, aS2, aD2, as2, ad2, N);
    }

    // 5) layer-2 fused softmax+aggregate (meta-free, wave-uniform shfl)
    gat_fused_l2<<<(N + 3) / 4, 256, 0, stream>>>(h2b, as2, ad2, counts, csr, b2, out, N);
}